// Round 9
// baseline (350.800 us; speedup 1.0000x reference)
//
#include <hip/hip_runtime.h>

// Problem constants
#define N_TOK 8192
#define N_EXP 8
#define DIM   2048
#define HID   2048

typedef __attribute__((ext_vector_type(8))) short short8;
typedef __attribute__((ext_vector_type(4))) float f32x4;
typedef __attribute__((ext_vector_type(4))) unsigned short ushort4v;

__device__ inline unsigned short f2bf(float f) {
  unsigned int u = __builtin_bit_cast(unsigned int, f);
  unsigned int r = u + 0x7FFFu + ((u >> 16) & 1u);   // round-to-nearest-even
  return (unsigned short)(r >> 16);
}

// ---------------------------------------------------------------------------
// Kernel 1: stable counting sort by expert id + 64-row band table + per-XCD
// work-queue counters.
// perm[p] = source row; offs[e..e+1] = bounds;
// bands[0] = nbands, bands[1+i] = e | (absRow << 8); qcnt[x] = 256.
// ---------------------------------------------------------------------------
__global__ __launch_bounds__(256) void sort_experts(const int* __restrict__ idx,
                                                    int* __restrict__ perm,
                                                    int* __restrict__ offs,
                                                    int* __restrict__ bands,
                                                    int* __restrict__ qcnt) {
  __shared__ int cnt[256][8];
  __shared__ int base[8];
  const int t = threadIdx.x;
  int local[8] = {0,0,0,0,0,0,0,0};
  const int r0 = t * 32;
  for (int i = 0; i < 32; ++i) {
    int e = idx[r0 + i] & 7;
    ++local[e];
  }
#pragma unroll
  for (int e = 0; e < 8; ++e) cnt[t][e] = local[e];
  __syncthreads();
  if (t < 8) {
    int s = 0;
    for (int i = 0; i < 256; ++i) { int v = cnt[i][t]; cnt[i][t] = s; s += v; }
    base[t] = s;
    qcnt[t] = 256;                       // per-XCD queue starts after slots
  }
  __syncthreads();
  if (t == 0) {
    int s = 0, nb = 0;
    for (int e = 0; e < 8; ++e) {
      int v = base[e];
      offs[e] = s; base[e] = s;
      int nm = (v + 63) >> 6;            // 64-row bands
      for (int mt = 0; mt < nm; ++mt) bands[1 + nb++] = e | ((s + mt * 64) << 8);
      s += v;
    }
    offs[8] = s;
    bands[0] = nb;
  }
  __syncthreads();
  int pos[8];
#pragma unroll
  for (int e = 0; e < 8; ++e) pos[e] = base[e] + cnt[t][e];
  for (int i = 0; i < 32; ++i) {
    int r = r0 + i;
    int e = idx[r] & 7;
    perm[pos[e]++] = r;
  }
}

// ---------------------------------------------------------------------------
// Kernel 2: merged prep. Blocks [0,8192): gather+convert x (sorted bf16).
// Blocks [8192,16384): W[e][d][h] fp32 -> Wt[e][h][d] bf16 (LDS transpose).
// ---------------------------------------------------------------------------
__global__ __launch_bounds__(256) void prep(const float* __restrict__ x,
                                            const int* __restrict__ perm,
                                            unsigned short* __restrict__ xs,
                                            const float* __restrict__ W,
                                            unsigned short* __restrict__ Wt) {
  __shared__ unsigned short tile[64][68];
  const int t = threadIdx.x;
  if (blockIdx.x < 8192) {
    int gid = blockIdx.x * 256 + t;
    int p = gid >> 8;
    int c = gid & 255;
    int src = perm[p];
    const float* sp = x + (size_t)src * DIM + c * 8;
    float4 a = *(const float4*)sp;
    float4 b = *(const float4*)(sp + 4);
    short8 o;
    o[0] = (short)f2bf(a.x); o[1] = (short)f2bf(a.y);
    o[2] = (short)f2bf(a.z); o[3] = (short)f2bf(a.w);
    o[4] = (short)f2bf(b.x); o[5] = (short)f2bf(b.y);
    o[6] = (short)f2bf(b.z); o[7] = (short)f2bf(b.w);
    *(short8*)(xs + (size_t)p * DIM + c * 8) = o;
  } else {
    const int b = blockIdx.x - 8192;
    const int e  = b >> 10;
    const int d0 = ((b >> 5) & 31) * 64;
    const int h0 = (b & 31) * 64;
    const int cr = t & 15;
    const int rr = t >> 4;
    const float* Wp = W + ((size_t)e * DIM + d0) * HID + h0;
#pragma unroll
    for (int i = 0; i < 4; ++i) {
      int d = rr + i * 16;
      float4 v = *(const float4*)(Wp + (size_t)d * HID + cr * 4);
      ushort4v o;
      o[0] = f2bf(v.x); o[1] = f2bf(v.y); o[2] = f2bf(v.z); o[3] = f2bf(v.w);
      *(ushort4v*)&tile[d][cr * 4] = o;
    }
    __syncthreads();
    unsigned short* op = Wt + ((size_t)e * HID + h0) * DIM + d0;
#pragma unroll
    for (int i = 0; i < 4; ++i) {
      int h = rr + i * 16;
      ushort4v o;
      o[0] = tile[cr * 4 + 0][h];
      o[1] = tile[cr * 4 + 1][h];
      o[2] = tile[cr * 4 + 2][h];
      o[3] = tile[cr * 4 + 3][h];
      *(ushort4v*)(op + (size_t)h * DIM + cr * 4) = o;
    }
  }
}

// ---------------------------------------------------------------------------
// Kernel 3: grouped GEMM, LDS-FREE. 512 blocks x 256 thr; every WAVE is an
// independent worker (no barriers, no LDS, no vmcnt drains). Wave-job =
// 64(M) x 128(N); all A/B fragments are contiguous 16B/lane in xs/Wt and are
// loaded straight to registers; compiler software-pipelines loads vs MFMA,
// 8 waves/CU provide TLP. XCD-affine: XCD x = blockIdx&7 owns nx {2x,2x+1};
// adjacent jobs share the A band; per-XCD work queue in qcnt[x].
// ---------------------------------------------------------------------------
#define MM(D,A,B) D = __builtin_amdgcn_mfma_f32_16x16x32_bf16(A, B, D, 0, 0, 0)

__global__ __launch_bounds__(256, 2) void grouped_gemm(
    const unsigned short* __restrict__ xs,
    const unsigned short* __restrict__ Wt,
    const float* __restrict__ bias,
    const int* __restrict__ offs,
    const int* __restrict__ bands,
    int* __restrict__ qcnt,
    float* __restrict__ out) {
  const int t    = threadIdx.x;
  const int lane = t & 63;
  const int w    = t >> 6;
  const int l15  = lane & 15;
  const int l4   = lane >> 4;
  const int xcd  = blockIdx.x & 7;

  const int nj = bands[0] * 2;           // jobs owned by each XCD
  int i = (blockIdx.x >> 3) * 4 + w;     // initial slot 0..255 within XCD

  while (i < nj) {
    const int bd   = bands[1 + (i >> 1)];
    const int e    = bd & 255;
    const int aRow = bd >> 8;            // absolute sorted row of band start
    const int hi   = offs[e + 1];        // absolute end of this expert
    const int nx   = (xcd << 1) | (i & 1);
    const int n0   = nx * 128;

    // Per-lane fragment bases (ushort elements). A rows may run past the
    // band/expert tail: reads stay inside ws (xs|Wt) and are masked at store.
    const unsigned short* pA = xs + (unsigned)(aRow + l15) * 2048u + l4 * 8;
    const unsigned short* pB = Wt + (size_t)e * ((size_t)DIM * HID)
                                  + (unsigned)(n0 + l15) * 2048u + l4 * 8;

    f32x4 acc[4][8];
#pragma unroll
    for (int m = 0; m < 4; ++m)
#pragma unroll
      for (int n = 0; n < 8; ++n) acc[m][n] = (f32x4){0.f, 0.f, 0.f, 0.f};

#pragma unroll 1
    for (int k = 0; k < 2048; k += 32) {
      short8 fa0 = *(const short8*)(pA + 0 * 32768 + k);
      short8 fa1 = *(const short8*)(pA + 1 * 32768 + k);
      short8 fa2 = *(const short8*)(pA + 2 * 32768 + k);
      short8 fa3 = *(const short8*)(pA + 3 * 32768 + k);
      short8 fb0 = *(const short8*)(pB + 0 * 32768 + k);
      short8 fb1 = *(const short8*)(pB + 1 * 32768 + k);
      short8 fb2 = *(const short8*)(pB + 2 * 32768 + k);
      short8 fb3 = *(const short8*)(pB + 3 * 32768 + k);
      short8 fb4 = *(const short8*)(pB + 4 * 32768 + k);
      short8 fb5 = *(const short8*)(pB + 5 * 32768 + k);
      short8 fb6 = *(const short8*)(pB + 6 * 32768 + k);
      short8 fb7 = *(const short8*)(pB + 7 * 32768 + k);
#pragma unroll
      for (int m = 0; m < 4; ++m) {
        const short8 fa = (m == 0) ? fa0 : (m == 1) ? fa1 : (m == 2) ? fa2 : fa3;
        MM(acc[m][0], fa, fb0); MM(acc[m][1], fa, fb1);
        MM(acc[m][2], fa, fb2); MM(acc[m][3], fa, fb3);
        MM(acc[m][4], fa, fb4); MM(acc[m][5], fa, fb5);
        MM(acc[m][6], fa, fb6); MM(acc[m][7], fa, fb7);
      }
    }

    // Epilogue: bias + relu; mask rows past the expert tail.
#pragma unroll
    for (int n = 0; n < 8; ++n) {
      int col = n0 + n * 16 + l15;
      float bv = bias[e * HID + col];
#pragma unroll
      for (int m = 0; m < 4; ++m) {
#pragma unroll
        for (int q = 0; q < 4; ++q) {
          int r = aRow + m * 16 + l4 * 4 + q;
          if (r < hi) {
            float v = acc[m][n][q] + bv;
            out[(size_t)r * HID + col] = v > 0.f ? v : 0.f;
          }
        }
      }
    }

    // Wave-level steal from this XCD's queue.
    int nx_i = 0;
    if (lane == 0) nx_i = atomicAdd(&qcnt[xcd], 1);
    i = __shfl(nx_i, 0);
  }
}

// ---------------------------------------------------------------------------
extern "C" void kernel_launch(void* const* d_in, const int* in_sizes, int n_in,
                              void* d_out, int out_size, void* d_ws, size_t ws_size,
                              hipStream_t stream) {
  const float* x   = (const float*)d_in[0];
  const int*   idx = (const int*)d_in[1];
  const float* W   = (const float*)d_in[2];
  const float* b   = (const float*)d_in[3];
  float* out = (float*)d_out;

  char* ws = (char*)d_ws;
  unsigned short* xs = (unsigned short*)ws;                                   // 32 MB
  unsigned short* Wt = (unsigned short*)(ws + (size_t)N_TOK * DIM * 2);       // 64 MB
  int* perm  = (int*)(ws + (size_t)N_TOK * DIM * 2 + (size_t)N_EXP * DIM * HID * 2);
  int* offs  = perm + N_TOK;
  int* bands = offs + 16;
  int* qcnt  = bands + 4096;

  sort_experts<<<1, 256, 0, stream>>>(idx, perm, offs, bands, qcnt);
  prep<<<16384, 256, 0, stream>>>(x, perm, xs, W, Wt);
  grouped_gemm<<<512, 256, 0, stream>>>(xs, Wt, b, offs, bands, qcnt, out);
}